// Round 9
// baseline (19379.735 us; speedup 1.0000x reference)
//
#include <hip/hip_runtime.h>
#include <hip/hip_bf16.h>

// Problem constants
#define BATCH 2048
#define NCH 64
#define MAXLEN 128
#define RDIM 256

// Workspace float offsets
#define WCAT_OFF 0        // [256 k][256 u][4 gates] (r,z combined Wih+Whh; i_n; h_n)
#define WHH0_OFF 262144   // [256 k][256 u][4] step-0 (Whh_r, Whh_z, Whh_n, 0)
#define WLH_OFF  524288   // [384 k][256 u]
#define WOUT_OFF 622592   // [256 k][64 o] transposed
#define BCAT_OFF 638976   // [256 u][4]
#define BCAT0_OFF 640000  // [256 u][4]

__global__ void prep_kernel(const float* __restrict__ W_lh,
                            const float* __restrict__ W_ih, const float* __restrict__ W_hh,
                            const float* __restrict__ b_ih, const float* __restrict__ b_hh,
                            const float* __restrict__ W_out, float* __restrict__ ws) {
    int gid = blockIdx.x * blockDim.x + threadIdx.x;   // 0..98303
    if (gid < 384 * 256) {
        int k = gid >> 8, u = gid & 255;
        ws[WLH_OFF + gid] = W_lh[u * 384 + k];
    }
    if (gid < 65536) {
        int k = gid >> 8, u = gid & 255;
        float ir = W_ih[u * 256 + k], iz = W_ih[(256 + u) * 256 + k], inw = W_ih[(512 + u) * 256 + k];
        float hr = W_hh[u * 256 + k], hz = W_hh[(256 + u) * 256 + k], hnw = W_hh[(512 + u) * 256 + k];
        int base = WCAT_OFF + k * 1024 + u * 4;
        ws[base + 0] = ir + hr; ws[base + 1] = iz + hz; ws[base + 2] = inw; ws[base + 3] = hnw;
        base = WHH0_OFF + k * 1024 + u * 4;
        ws[base + 0] = hr; ws[base + 1] = hz; ws[base + 2] = hnw; ws[base + 3] = 0.0f;
    }
    if (gid < 16384) {
        int o = gid & 63, k = gid >> 6;
        ws[WOUT_OFF + k * 64 + o] = W_out[o * 256 + k];   // transpose to [k][o]
    }
    if (gid < 256) {
        int u = gid;
        float bir = b_ih[u], biz = b_ih[256 + u];
        float bhr = b_hh[u], bhz = b_hh[256 + u], bhn = b_hh[512 + u];
        int base = BCAT_OFF + u * 4;
        ws[base + 0] = bir + bhr; ws[base + 1] = biz + bhz; ws[base + 2] = b_ih[512 + u]; ws[base + 3] = bhn;
        base = BCAT0_OFF + u * 4;
        ws[base + 0] = bir + bhr; ws[base + 1] = biz + bhz; ws[base + 2] = bhn; ws[base + 3] = 0.0f;
    }
}

__device__ __forceinline__ float sigm(float x)   { return 1.0f / (1.0f + __expf(-x)); }
__device__ __forceinline__ float tanh_f(float x) { return 1.0f - 2.0f / (1.0f + __expf(2.0f * x)); }

// 256 wgs x 1024 threads. Thread (u = tid&255, q = tid>>8):
//   GEMM: rows rotated (2q+jj)&7 over k-slice [q*64, q*64+64); own rows at slots 0,1.
//   Weight loads: wave-uniform row base (saddr-form) + [u] voffset; register
//   ping-pong prefetch (c*/d*) so next k4's loads are in flight during FMAs.
//   partials for slots 2..7 -> LDS; distributed reduce; biases in epilogue.
//   logits: half-k partials, 4 indep chains, combine after barrier.
__global__ __launch_bounds__(1024, 1)
void gru_persist(const float* __restrict__ z, const float* __restrict__ xc,
                 const float* __restrict__ b_lh, const float* __restrict__ b_ih,
                 const float* __restrict__ b_out_g,
                 const float* __restrict__ ws, float* __restrict__ out) {
    __shared__ __align__(16) float lds_h[8 * 256];        // 8 KB
    __shared__ __align__(16) float4 pbufv[4 * 6 * 256];   // 96 KB partials (head reused for zc)
    __shared__ float lbuf[1024];                          // 4 KB logit partials

    const int tid = threadIdx.x;
    const int u   = tid & 255;
    const int q   = __builtin_amdgcn_readfirstlane(tid >> 8);   // wave-uniform -> SGPR
    const int b0  = blockIdx.x * 8;

    // ---- stage zc = [z | x_cond] rows b0..b0+7 into pbufv-as-float [i][384]
    float* zcs = (float*)pbufv;
    for (int idx = tid; idx < 8 * 384; idx += 1024) {
        int i = idx / 384, k = idx - i * 384;
        zcs[idx] = (k < 256) ? z[(b0 + i) * 256 + k] : xc[(b0 + i) * 128 + (k - 256)];
    }
    __syncthreads();

    // ---- h0 for own rows 2q, 2q+1 (uniform-base weight loads)
    float h_own0, h_own1;
    {
        float a0 = b_lh[u], a1 = a0;
        const float* zr0 = zcs + (2 * q) * 384;
        const float* zr1 = zr0 + 384;
#pragma unroll 2
        for (int k4 = 0; k4 < 96; ++k4) {
            const int k = 4 * k4;
            const float* wr = ws + WLH_OFF + k * 256;    // uniform base
            float w0 = wr[u];
            float w1 = wr[256 + u];
            float w2 = wr[512 + u];
            float w3 = wr[768 + u];
            const float4 v0 = *(const float4*)(zr0 + k);
            const float4 v1 = *(const float4*)(zr1 + k);
            a0 += v0.x * w0 + v0.y * w1 + v0.z * w2 + v0.w * w3;
            a1 += v1.x * w0 + v1.y * w1 + v1.z * w2 + v1.w * w3;
        }
        h_own0 = a0; h_own1 = a1;
        lds_h[(2 * q) * 256 + u] = a0;
        lds_h[(2 * q + 1) * 256 + u] = a1;
    }
    __syncthreads();   // zc reads done, h0 visible, pbufv free

    const float4* Wcat  = (const float4*)(ws + WCAT_OFF);
    const float4* Whh0v = (const float4*)(ws + WHH0_OFF);
    const float4  bc1   = ((const float4*)(ws + BCAT_OFF))[u];
    const float4  bc0v  = ((const float4*)(ws + BCAT0_OFF))[u];
    const float   bin_c = b_ih[512 + u];

    int ro[8];   // slot jj -> LDS row offset of batch row (2q+jj)&7  (q is SGPR)
#pragma unroll
    for (int jj = 0; jj < 8; ++jj) ro[jj] = (((2 * q + jj) & 7) << 8);
    const int kb = q * 64;

    // logits-partial mapping: thread -> output p=tid>>1 (r=p>>6,o=p&63), k-half kh=tid&1
    const int lkh = tid & 1;
    const int lo_o = (tid >> 1) & 63;
    const float* hrow_base = lds_h + ((tid >> 1) >> 6) * 256 + lkh * 128;
    const float* wTb = ws + WOUT_OFF;                  // uniform base
    const int wofs = lkh * 128 * 64 + lo_o;            // per-lane offset (one reg)
    // combine mapping (tid<512): output (cr, co)
    const int co = tid & 63, cr = tid >> 6;
    const float bout = b_out_g[co];
    float* outp = out + (long)b0 * MAXLEN * NCH;

    for (int st = 0; st < MAXLEN; ++st) {
        const float4* Wp = st ? Wcat : Whh0v;
        float ax[8], ay[8], az[8], aw[8];
#pragma unroll
        for (int jj = 0; jj < 8; ++jj) { ax[jj] = 0.f; ay[jj] = 0.f; az[jj] = 0.f; aw[jj] = 0.f; }

        const float* hbase = lds_h + kb;

        // ---- GEMM over own k-slice, uniform-base loads + c/d register ping-pong
        const float4* wr0 = Wp + kb * 256;             // uniform (kb, Wp SGPR-derived)
        float4 c0 = wr0[u], c1 = wr0[256 + u], c2 = wr0[512 + u], c3 = wr0[768 + u];
        float4 d0, d1, d2, d3;
#pragma unroll 2
        for (int k8 = 0; k8 < 8; ++k8) {
            // --- sub-iter A: k4 = 2*k8, compute with c*, prefetch d* (k4+1)
            {
                const float4* wn = Wp + (kb + 8 * k8 + 4) * 256;
                d0 = wn[u]; d1 = wn[256 + u]; d2 = wn[512 + u]; d3 = wn[768 + u];
                const int kOff = 8 * k8;
#pragma unroll
                for (int jj = 0; jj < 8; ++jj) {
                    const float4 hv = *(const float4*)(hbase + ro[jj] + kOff);
                    ax[jj] += hv.x * c0.x; ay[jj] += hv.x * c0.y; az[jj] += hv.x * c0.z; aw[jj] += hv.x * c0.w;
                    ax[jj] += hv.y * c1.x; ay[jj] += hv.y * c1.y; az[jj] += hv.y * c1.z; aw[jj] += hv.y * c1.w;
                    ax[jj] += hv.z * c2.x; ay[jj] += hv.z * c2.y; az[jj] += hv.z * c2.z; aw[jj] += hv.z * c2.w;
                    ax[jj] += hv.w * c3.x; ay[jj] += hv.w * c3.y; az[jj] += hv.w * c3.z; aw[jj] += hv.w * c3.w;
                }
            }
            // --- sub-iter B: k4 = 2*k8+1, compute with d*, prefetch c* (k4+1)
            {
                if (k8 < 7) {
                    const float4* wn = Wp + (kb + 8 * k8 + 8) * 256;
                    c0 = wn[u]; c1 = wn[256 + u]; c2 = wn[512 + u]; c3 = wn[768 + u];
                }
                const int kOff = 8 * k8 + 4;
#pragma unroll
                for (int jj = 0; jj < 8; ++jj) {
                    const float4 hv = *(const float4*)(hbase + ro[jj] + kOff);
                    ax[jj] += hv.x * d0.x; ay[jj] += hv.x * d0.y; az[jj] += hv.x * d0.z; aw[jj] += hv.x * d0.w;
                    ax[jj] += hv.y * d1.x; ay[jj] += hv.y * d1.y; az[jj] += hv.y * d1.z; aw[jj] += hv.y * d1.w;
                    ax[jj] += hv.z * d2.x; ay[jj] += hv.z * d2.y; az[jj] += hv.z * d2.z; aw[jj] += hv.z * d2.w;
                    ax[jj] += hv.w * d3.x; ay[jj] += hv.w * d3.y; az[jj] += hv.w * d3.z; aw[jj] += hv.w * d3.w;
                }
            }
        }

        // ---- write partials for the 6 non-own rows (slot j+2 -> row (2q+2+j)&7)
        {
            float4* pb = pbufv + q * 6 * 256 + u;
#pragma unroll
            for (int j = 0; j < 6; ++j)
                pb[j * 256] = make_float4(ax[j + 2], ay[j + 2], az[j + 2], aw[j + 2]);
        }

        // ---- logits partial of PREVIOUS step's h (old lds_h); 4 indep chains
        if (st) {
            float l0 = 0.f, l1 = 0.f, l2 = 0.f, l3 = 0.f;
#pragma unroll 8
            for (int kk = 0; kk < 32; ++kk) {
                const float4 hval = *(const float4*)&hrow_base[4 * kk];
                l0 += hval.x * wTb[(4 * kk + 0) * 64 + wofs];
                l1 += hval.y * wTb[(4 * kk + 1) * 64 + wofs];
                l2 += hval.z * wTb[(4 * kk + 2) * 64 + wofs];
                l3 += hval.w * wTb[(4 * kk + 3) * 64 + wofs];
            }
            lbuf[tid] = (l0 + l1) + (l2 + l3);
        }

        __syncthreads();   // A: partials + logit-partials visible; all old-h reads done

        // ---- distributed reduce + epilogue for own rows (slots 0,1)
#pragma unroll
        for (int qq = 0; qq < 4; ++qq) {
            if (qq != q) {
                const int j0 = (2 * q - 2 * qq - 2) & 7;       // in {0,2,4}
                const float4 p0 = pbufv[(qq * 6 + j0) * 256 + u];
                const float4 p1 = pbufv[(qq * 6 + j0 + 1) * 256 + u];
                ax[0] += p0.x; ay[0] += p0.y; az[0] += p0.z; aw[0] += p0.w;
                ax[1] += p1.x; ay[1] += p1.y; az[1] += p1.z; aw[1] += p1.w;
            }
        }
        float hn0, hn1;
        if (st == 0) {
            float r0 = sigm(ax[0] + bc0v.x), z0 = sigm(ay[0] + bc0v.y);
            float n0 = tanh_f(bin_c + r0 * (az[0] + bc0v.z));
            hn0 = (1.f - z0) * n0 + z0 * h_own0;
            float r1 = sigm(ax[1] + bc0v.x), z1 = sigm(ay[1] + bc0v.y);
            float n1 = tanh_f(bin_c + r1 * (az[1] + bc0v.z));
            hn1 = (1.f - z1) * n1 + z1 * h_own1;
        } else {
            float r0 = sigm(ax[0] + bc1.x), z0 = sigm(ay[0] + bc1.y);
            float n0 = tanh_f(az[0] + bc1.z + r0 * (aw[0] + bc1.w));
            hn0 = (1.f - z0) * n0 + z0 * h_own0;
            float r1 = sigm(ax[1] + bc1.x), z1 = sigm(ay[1] + bc1.y);
            float n1 = tanh_f(az[1] + bc1.z + r1 * (aw[1] + bc1.w));
            hn1 = (1.f - z1) * n1 + z1 * h_own1;
        }
        lds_h[(2 * q) * 256 + u] = hn0;
        lds_h[(2 * q + 1) * 256 + u] = hn1;
        h_own0 = hn0; h_own1 = hn1;

        // ---- combine + store previous step's logits
        if (st && tid < 512) {
            float l = lbuf[2 * tid] + lbuf[2 * tid + 1] + bout;
            outp[(long)cr * MAXLEN * NCH + (st - 1) * NCH + co] = l;
        }
        __syncthreads();   // B: new h visible; lbuf consumed
    }

    // ---- final step's logits (from final lds_h)
    {
        float l0 = 0.f, l1 = 0.f, l2 = 0.f, l3 = 0.f;
#pragma unroll 8
        for (int kk = 0; kk < 32; ++kk) {
            const float4 hval = *(const float4*)&hrow_base[4 * kk];
            l0 += hval.x * wTb[(4 * kk + 0) * 64 + wofs];
            l1 += hval.y * wTb[(4 * kk + 1) * 64 + wofs];
            l2 += hval.z * wTb[(4 * kk + 2) * 64 + wofs];
            l3 += hval.w * wTb[(4 * kk + 3) * 64 + wofs];
        }
        lbuf[tid] = (l0 + l1) + (l2 + l3);
    }
    __syncthreads();
    if (tid < 512) {
        float l = lbuf[2 * tid] + lbuf[2 * tid + 1] + bout;
        outp[(long)cr * MAXLEN * NCH + (MAXLEN - 1) * NCH + co] = l;
    }
}

extern "C" void kernel_launch(void* const* d_in, const int* in_sizes, int n_in,
                              void* d_out, int out_size, void* d_ws, size_t ws_size,
                              hipStream_t stream) {
    const float* z     = (const float*)d_in[0];
    const float* xcond = (const float*)d_in[1];
    const float* W_lh  = (const float*)d_in[2];
    const float* b_lh  = (const float*)d_in[3];
    const float* W_ih  = (const float*)d_in[4];
    const float* W_hh  = (const float*)d_in[5];
    const float* b_ih  = (const float*)d_in[6];
    const float* b_hh  = (const float*)d_in[7];
    const float* W_out = (const float*)d_in[8];
    const float* b_out = (const float*)d_in[9];
    float* out = (float*)d_out;
    float* ws  = (float*)d_ws;

    hipLaunchKernelGGL(prep_kernel, dim3(384), dim3(256), 0, stream,
                       W_lh, W_ih, W_hh, b_ih, b_hh, W_out, ws);
    hipLaunchKernelGGL(gru_persist, dim3(256), dim3(1024), 0, stream,
                       z, xcond, b_lh, b_ih, b_out, ws, out);
}

// Round 10
// 3130.425 us; speedup vs baseline: 6.1908x; 6.1908x over previous
//
#include <hip/hip_runtime.h>
#include <hip/hip_bf16.h>

// Problem constants
#define BATCH 2048
#define NCH 64
#define MAXLEN 128
#define RDIM 256

// Workspace layout:
//  bytes [0, 1MB):      bf16 B-fragment stream for steps >=1 (Wcat split [W_hi | W_lo])
//  bytes [1MB, 2MB):    bf16 B-fragment stream for step 0   (Whh0 split)
//  float index 524288:  WLH   [384 k][256 u]
//  float index 622592:  WOUTT [256 k][64 o]
//  float index 638976:  BCAT  [256 u][4]
//  float index 640000:  BCAT0 [256 u][4]
#define WLHf   524288
#define WOUTf  622592
#define BCATf  638976
#define BCAT0f 640000

typedef short s8v  __attribute__((ext_vector_type(8)));   // 8 bf16 (4 VGPR)
typedef float f4v  __attribute__((ext_vector_type(4)));   // MFMA accumulator

__device__ __forceinline__ unsigned short f2bf(float x) {   // RNE f32->bf16 bits
    union { float f; unsigned int u; } c; c.f = x;
    unsigned int r = c.u + 0x7fffu + ((c.u >> 16) & 1u);
    return (unsigned short)(r >> 16);
}
__device__ __forceinline__ float bf2f(unsigned short b) {
    union { unsigned int u; float f; } c; c.u = ((unsigned int)b) << 16; return c.f;
}
__device__ __forceinline__ float sigm(float x)   { return 1.0f / (1.0f + __expf(-x)); }
__device__ __forceinline__ float tanh_f(float x) { return 1.0f - 2.0f / (1.0f + __expf(2.0f * x)); }

// B-fragment stream order: ushort idx = (((w*16 + ks)*4 + g)*64 + lane)*8 + j
//  wave w owns units [16w,16w+16); tile (g): cols = units, gate g; k' = ks*32 + (lane>>4)*8 + j
//  k' < 256 -> W_hi[k'], else W_lo[k'-256]  (A' = [h|h], B' = [W_hi|W_lo] split-K)
__global__ void prep_kernel(const float* __restrict__ W_lh,
                            const float* __restrict__ W_ih, const float* __restrict__ W_hh,
                            const float* __restrict__ b_ih, const float* __restrict__ b_hh,
                            const float* __restrict__ W_out, float* __restrict__ ws) {
    int gid = blockIdx.x * blockDim.x + threadIdx.x;   // 0..524287
    unsigned short* st_cat = (unsigned short*)ws;
    unsigned short* st_0   = (unsigned short*)ws + 524288;
    {
        const int j  = gid & 7;
        const int l  = (gid >> 3) & 63;
        const int g  = (gid >> 9) & 3;
        const int q2 = gid >> 11;                 // w*16 + ks, in [0,256)
        const int ks = q2 & 15;
        const int w  = q2 >> 4;
        const int u  = 16 * w + (l & 15);
        const int kp = ks * 32 + ((l >> 4) << 3) + j;   // k' in [0,512)
        const int blk = kp >> 8, kk = kp & 255;
        float vc, v0;
        if (g == 0)      { vc = W_ih[u*256+kk] + W_hh[u*256+kk];             v0 = W_hh[u*256+kk]; }
        else if (g == 1) { vc = W_ih[(256+u)*256+kk] + W_hh[(256+u)*256+kk]; v0 = W_hh[(256+u)*256+kk]; }
        else if (g == 2) { vc = W_ih[(512+u)*256+kk];                        v0 = W_hh[(512+u)*256+kk]; }
        else             { vc = W_hh[(512+u)*256+kk];                        v0 = 0.0f; }
        unsigned short ch = f2bf(vc), oh = f2bf(v0);
        st_cat[gid] = blk ? f2bf(vc - bf2f(ch)) : ch;
        st_0[gid]   = blk ? f2bf(v0 - bf2f(oh)) : oh;
    }
    if (gid < 98304) ws[WLHf + gid] = W_lh[(gid & 255) * 384 + (gid >> 8)];       // [k][u]
    if (gid < 16384) ws[WOUTf + (gid >> 6) * 64 + (gid & 63)] = W_out[(gid & 63) * 256 + (gid >> 6)];
    if (gid < 256) {
        int u = gid;
        float bir = b_ih[u], biz = b_ih[256 + u];
        float bhr = b_hh[u], bhz = b_hh[256 + u], bhn = b_hh[512 + u];
        ws[BCATf  + u*4 + 0] = bir + bhr; ws[BCATf  + u*4 + 1] = biz + bhz;
        ws[BCATf  + u*4 + 2] = b_ih[512 + u]; ws[BCATf + u*4 + 3] = bhn;
        ws[BCAT0f + u*4 + 0] = bir + bhr; ws[BCAT0f + u*4 + 1] = biz + bhz;
        ws[BCAT0f + u*4 + 2] = bhn;           ws[BCAT0f + u*4 + 3] = 0.0f;
    }
}

// 256 wgs x 1024 threads (16 waves). wg owns 8 batch rows; M padded to 16 (rows 8-15 zero).
// GEMM: wave w computes 4 tiles (gate g=0..3) of D[16 rows][units 16w..16w+16), K'=512 (W-split).
// D layout (verified): col=lane&15 (unit), row=(lane>>4)*4+reg -> lanes 0..31 hold real rows 0..7.
// Epilogue lane-local (all 4 gates same lane); h kept f32 in regs (hp[4]) + lds_h (logits).
// A-frags (bf16 h) staged in LDS [32 octets][16 rows][8] +8 pad/octet; rebuilt each step.
// Logits: R6's pipelined VALU path, verbatim.
__global__ __launch_bounds__(1024, 1)
void gru_persist(const float* __restrict__ z, const float* __restrict__ xc,
                 const float* __restrict__ b_lh, const float* __restrict__ b_ih,
                 const float* __restrict__ b_out_g,
                 const float* __restrict__ ws, float* __restrict__ out) {
    __shared__ float lds_h[8 * 256];                 // 8 KB, f32 h (logits + h0 handoff)
    __shared__ unsigned short A2[32 * 136];          // 8.7 KB, A-fragment staging (bf16)
    __shared__ float zcs[8 * 384];                   // 12 KB, zc staging (h0 only)
    __shared__ float lbuf[1024];                     // 4 KB, logit partials

    const int tid  = threadIdx.x;
    const int u_t  = tid & 255;                              // h0-phase unit
    const int q    = __builtin_amdgcn_readfirstlane(tid >> 8);
    const int wave = __builtin_amdgcn_readfirstlane(tid >> 6);
    const int lane = tid & 63;
    const int b0   = blockIdx.x * 8;
    const int colc   = lane & 15;
    const int krow   = lane >> 4;            // 0..3
    const int unit_g = 16 * wave + colc;     // GEMM-lane unit
    const int r_base = krow * 4;             // D rows r_base..r_base+3 (lanes<32 real)

    // ---- stage zc rows b0..b0+7
    for (int idx = tid; idx < 8 * 384; idx += 1024) {
        int i = idx / 384, k = idx - i * 384;
        zcs[idx] = (k < 256) ? z[(b0 + i) * 256 + k] : xc[(b0 + i) * 128 + (k - 256)];
    }
    // zero A-staging (incl. pad rows 8-15)
    for (int i = tid; i < 32 * 136; i += 1024) A2[i] = 0;
    __syncthreads();

    // ---- h0 (VALU, R6 form): thread (u_t, q) -> rows 2q, 2q+1
    {
        float a0 = b_lh[u_t], a1 = a0;
        const float* zr0 = zcs + (2 * q) * 384;
        const float* zr1 = zr0 + 384;
#pragma unroll 2
        for (int k4 = 0; k4 < 96; ++k4) {
            const int k = 4 * k4;
            const float* wr = ws + WLHf + k * 256;
            float w0 = wr[u_t], w1 = wr[256 + u_t], w2 = wr[512 + u_t], w3 = wr[768 + u_t];
            const float4 v0 = *(const float4*)(zr0 + k);
            const float4 v1 = *(const float4*)(zr1 + k);
            a0 += v0.x * w0 + v0.y * w1 + v0.z * w2 + v0.w * w3;
            a1 += v1.x * w0 + v1.y * w1 + v1.z * w2 + v1.w * w3;
        }
        lds_h[(2 * q) * 256 + u_t] = a0;
        lds_h[(2 * q + 1) * 256 + u_t] = a1;
    }
    __syncthreads();

    // ---- fill A-staging from h0; load h_prev regs
    for (int idx = tid; idx < 2048; idx += 1024) {
        const int row = idx >> 8, uu = idx & 255;
        A2[(uu >> 3) * 136 + row * 8 + (uu & 7)] = f2bf(lds_h[row * 256 + uu]);
    }
    float hp0 = 0.f, hp1 = 0.f, hp2 = 0.f, hp3 = 0.f;
    if (lane < 32) {
        hp0 = lds_h[(r_base + 0) * 256 + unit_g];
        hp1 = lds_h[(r_base + 1) * 256 + unit_g];
        hp2 = lds_h[(r_base + 2) * 256 + unit_g];
        hp3 = lds_h[(r_base + 3) * 256 + unit_g];
    }
    __syncthreads();

    // per-lane epilogue constants
    const float4 bc1 = ((const float4*)(ws + BCATf))[unit_g];
    const float4 bc0 = ((const float4*)(ws + BCAT0f))[unit_g];
    const float  binc = b_ih[512 + unit_g];

    // logits mapping (R6 verbatim)
    const int lkh = tid & 1;
    const int lo_o = (tid >> 1) & 63;
    const float* hrow_base = lds_h + ((tid >> 1) >> 6) * 256 + lkh * 128;
    const float* wTb = ws + WOUTf;
    const int wofs = lkh * 128 * 64 + lo_o;
    const int co = tid & 63, cr = tid >> 6;
    const float bout = b_out_g[co];
    float* outp = out + (long)b0 * MAXLEN * NCH;

    const int wbase = wave * 4096;    // short8 units: wave*16*4*64

    for (int st = 0; st < MAXLEN; ++st) {
        const s8v* Wsv = (const s8v*)((const char*)ws + (st ? 0u : (1u << 20)));
        f4v ac0 = {0.f, 0.f, 0.f, 0.f}, ac1 = ac0, ac2 = ac0, ac3 = ac0;

        // ---- MFMA GEMM: 16 k'-steps x 4 gate-tiles
#pragma unroll 2
        for (int ks = 0; ks < 16; ++ks) {
            const int ksb = ks & 7;
            const s8v af = *(const s8v*)&A2[(4 * ksb + krow) * 136 + colc * 8];
            const s8v* bp = Wsv + wbase + ks * 256 + lane;
            s8v bf0 = bp[0], bf1 = bp[64], bf2 = bp[128], bf3 = bp[192];
            ac0 = __builtin_amdgcn_mfma_f32_16x16x32_bf16(af, bf0, ac0, 0, 0, 0);
            ac1 = __builtin_amdgcn_mfma_f32_16x16x32_bf16(af, bf1, ac1, 0, 0, 0);
            ac2 = __builtin_amdgcn_mfma_f32_16x16x32_bf16(af, bf2, ac2, 0, 0, 0);
            ac3 = __builtin_amdgcn_mfma_f32_16x16x32_bf16(af, bf3, ac3, 0, 0, 0);
        }

        // ---- logits partial of PREVIOUS step's h (old lds_h); 4 indep chains
        if (st) {
            float l0 = 0.f, l1 = 0.f, l2 = 0.f, l3 = 0.f;
#pragma unroll 8
            for (int kk = 0; kk < 32; ++kk) {
                const float4 hval = *(const float4*)&hrow_base[4 * kk];
                l0 += hval.x * wTb[(4 * kk + 0) * 64 + wofs];
                l1 += hval.y * wTb[(4 * kk + 1) * 64 + wofs];
                l2 += hval.z * wTb[(4 * kk + 2) * 64 + wofs];
                l3 += hval.w * wTb[(4 * kk + 3) * 64 + wofs];
            }
            lbuf[tid] = (l0 + l1) + (l2 + l3);
        }

        __syncthreads();   // A: all reads of old lds_h / A2 done

        // ---- epilogue: lanes<32 own rows r_base..r_base+3 of unit_g
        if (lane < 32) {
            float hpn0, hpn1, hpn2, hpn3;
#pragma unroll
            for (int j = 0; j < 4; ++j) {
                const float g0 = ac0[j], g1 = ac1[j], g2 = ac2[j], g3 = ac3[j];
                const float hpj = (j == 0) ? hp0 : (j == 1) ? hp1 : (j == 2) ? hp2 : hp3;
                float hn;
                if (st == 0) {
                    const float r = sigm(g0 + bc0.x), zz = sigm(g1 + bc0.y);
                    hn = (1.f - zz) * tanh_f(binc + r * (g2 + bc0.z)) + zz * hpj;
                } else {
                    const float r = sigm(g0 + bc1.x), zz = sigm(g1 + bc1.y);
                    hn = (1.f - zz) * tanh_f(g2 + bc1.z + r * (g3 + bc1.w)) + zz * hpj;
                }
                const int row = r_base + j;
                lds_h[row * 256 + unit_g] = hn;
                A2[(unit_g >> 3) * 136 + row * 8 + (unit_g & 7)] = f2bf(hn);
                if (j == 0) hpn0 = hn; else if (j == 1) hpn1 = hn; else if (j == 2) hpn2 = hn; else hpn3 = hn;
            }
            hp0 = hpn0; hp1 = hpn1; hp2 = hpn2; hp3 = hpn3;
        }

        // ---- combine + store previous step's logits
        if (st && tid < 512) {
            float l = lbuf[2 * tid] + lbuf[2 * tid + 1] + bout;
            outp[(long)cr * MAXLEN * NCH + (st - 1) * NCH + co] = l;
        }
        __syncthreads();   // B: new h / A2 visible
    }

    // ---- final step's logits
    {
        float l0 = 0.f, l1 = 0.f, l2 = 0.f, l3 = 0.f;
#pragma unroll 8
        for (int kk = 0; kk < 32; ++kk) {
            const float4 hval = *(const float4*)&hrow_base[4 * kk];
            l0 += hval.x * wTb[(4 * kk + 0) * 64 + wofs];
            l1 += hval.y * wTb[(4 * kk + 1) * 64 + wofs];
            l2 += hval.z * wTb[(4 * kk + 2) * 64 + wofs];
            l3 += hval.w * wTb[(4 * kk + 3) * 64 + wofs];
        }
        lbuf[tid] = (l0 + l1) + (l2 + l3);
    }
    __syncthreads();
    if (tid < 512) {
        float l = lbuf[2 * tid] + lbuf[2 * tid + 1] + bout;
        outp[(long)cr * MAXLEN * NCH + (MAXLEN - 1) * NCH + co] = l;
    }
}

extern "C" void kernel_launch(void* const* d_in, const int* in_sizes, int n_in,
                              void* d_out, int out_size, void* d_ws, size_t ws_size,
                              hipStream_t stream) {
    const float* z     = (const float*)d_in[0];
    const float* xcond = (const float*)d_in[1];
    const float* W_lh  = (const float*)d_in[2];
    const float* b_lh  = (const float*)d_in[3];
    const float* W_ih  = (const float*)d_in[4];
    const float* W_hh  = (const float*)d_in[5];
    const float* b_ih  = (const float*)d_in[6];
    const float* b_hh  = (const float*)d_in[7];
    const float* W_out = (const float*)d_in[8];
    const float* b_out = (const float*)d_in[9];
    float* out = (float*)d_out;
    float* ws  = (float*)d_ws;

    hipLaunchKernelGGL(prep_kernel, dim3(2048), dim3(256), 0, stream,
                       W_lh, W_ih, W_hh, b_ih, b_hh, W_out, ws);
    hipLaunchKernelGGL(gru_persist, dim3(256), dim3(1024), 0, stream,
                       z, xcond, b_lh, b_ih, b_out, ws, out);
}